// Round 15
// baseline (328.971 us; speedup 1.0000x reference)
//
#include <hip/hip_runtime.h>
#include <stdint.h>

// LIIF fused inference for MI355X (gfx950).
// B=4, C=64, H=W=128, Q=30000, HID=256, IN_DIM=580.
//
// v14 = v10 (best: 311us) minus redundant barriers, no setprio (v13: neutral).
// Collective-barrier analysis: the layer-loop ping-pong needs only 2 barriers/layer
// (after t0-kloop, after t1-kloop); the loop-end barrier was redundant. One final
// barrier before the ensemble covers predp.
// Register-box conclusion stands (v7/v8/v12: bulk breg+acc ~200 regs -> 2 waves/SIMD
// ceiling; forcing more spills to scratch). v11 32x32: neutral. v13 setprio: neutral.
//
// ws layout (33,996,800 bytes used):
//   h1_pre bf16  [0,        33554432)
//   W2t    bf16  [33554432, 33603584)   [256][96]
//   w2t    bf16  [33603584, 33734656)   [256][256]  (w2t[o][k] = w2[k][o])
//   w3t    bf16  [33734656, 33865728)
//   w4t    bf16  [33865728, 33996800)

typedef unsigned short u16;
typedef __attribute__((ext_vector_type(8))) short   short8;
typedef __attribute__((ext_vector_type(8))) __bf16  bf16x8;
typedef __attribute__((ext_vector_type(4))) float   f32x4;

__device__ __forceinline__ float bf2f(u16 u) {
  union { uint32_t i; float f; } v; v.i = ((uint32_t)u) << 16; return v.f;
}
__device__ __forceinline__ u16 f2bf(float f) {            // manual RNE (cold kernels)
  union { float f; uint32_t i; } v; v.f = f;
  return (u16)((v.i + 0x7FFFu + ((v.i >> 16) & 1u)) >> 16);
}
__device__ __forceinline__ u16 bfbits(float f) {          // native cast (hot kernel)
  union { __bf16 h; u16 u; } c; c.h = (__bf16)f; return c.u;
}

// ---------------------------------------------------------------- weights prep
__global__ void prep_weights(const float* __restrict__ w1, const float* __restrict__ w2,
                             const float* __restrict__ w3, const float* __restrict__ w4,
                             const float* __restrict__ cw, const float* __restrict__ cb,
                             u16* __restrict__ W2t, u16* __restrict__ w2t,
                             u16* __restrict__ w3t, u16* __restrict__ w4t) {
  int tid = blockIdx.x * 256 + threadIdx.x;
  if (tid < 24576) {
    int o = tid / 96, k = tid - o * 96;
    float s = 0.0f;
    if (k < 90) {
      int t = k / 10, j = k - t * 10;
      if (j == 9) {
        for (int c = 0; c < 64; ++c) s += cb[c] * w1[(c * 9 + t) * 256 + o];
      } else {
        for (int c = 0; c < 64; ++c) s += cw[c * 9 + j] * w1[(c * 9 + t) * 256 + o];
      }
    }
    W2t[o * 96 + k] = f2bf(s);
  } else {
    int u = tid - 24576;
    if (u < 3 * 65536) {
      int layer = u >> 16, r = u & 65535;
      int o = r >> 8, k = r & 255;
      const float* src = (layer == 0) ? w2 : (layer == 1) ? w3 : w4;
      u16* dst = (layer == 0) ? w2t : (layer == 1) ? w3t : w4t;
      dst[o * 256 + k] = f2bf(src[k * 256 + o]);
    }
  }
}

// ---------------------------------------------------------------- h1pre: composed K=96 GEMM
__global__ __launch_bounds__(256) void h1pre_kernel(const float* __restrict__ inp,
                                                    const u16* __restrict__ W2t,
                                                    const float* __restrict__ b1,
                                                    u16* __restrict__ h1pre) {
  __shared__ short Al[64 * 120];   // row = 120 shorts = 240 B

  int tid = threadIdx.x;
  int lane = tid & 63, wave = tid >> 6;
  int g = lane >> 4, l15 = lane & 15;
  int wc0 = wave * 64;
  int bid = blockIdx.x;
  int b = bid >> 8, rem = bid & 255;
  int y = rem >> 1, x0 = (rem & 1) << 6;

  // ---- build A: 4 threads per pixel, thread q covers k = q*24 .. q*24+23
  {
    int px = tid >> 2, q = tid & 3;
    int x = x0 + px;
    const float* ip = inp + b * 16384;
    #pragma unroll
    for (int c8 = 0; c8 < 3; ++c8) {
      short8 av;
      #pragma unroll
      for (int e = 0; e < 8; ++e) {
        int k = q * 24 + c8 * 8 + e;
        float val = 0.0f;
        if (k < 90) {
          int t = k / 10, j = k - t * 10;
          int dh = t / 3 - 1, dw = t % 3 - 1;
          int yy = y + dh, xx = x + dw;
          bool m = (yy >= 0) && (yy < 128) && (xx >= 0) && (xx < 128);
          if (j == 9) {
            val = m ? 1.0f : 0.0f;
          } else {
            int sh = j / 3 - 1, sw = j % 3 - 1;
            int r = yy + sh, c = xx + sw;
            val = (m && r >= 0 && r < 128 && c >= 0 && c < 128) ? ip[r * 128 + c] : 0.0f;
          }
        }
        av[e] = (short)f2bf(val);
      }
      *(short8*)(&Al[px * 120 + q * 24 + c8 * 8]) = av;
    }
  }
  __syncthreads();

  // ---- GEMM: K=96 in 3 k-steps, bulk breg[12], operand-swapped 16x16 MFMA
  bf16x8 breg[12];
  #pragma unroll
  for (int ks = 0; ks < 3; ++ks)
    #pragma unroll
    for (int nf = 0; nf < 4; ++nf)
      breg[ks * 4 + nf] =
          *(const bf16x8*)(W2t + (wc0 + nf * 16 + l15) * 96 + ks * 32 + g * 8);

  f32x4 acc[4][4];
  #pragma unroll
  for (int mf = 0; mf < 4; ++mf)
    #pragma unroll
    for (int nf = 0; nf < 4; ++nf) acc[mf][nf] = (f32x4){0.f, 0.f, 0.f, 0.f};

  #pragma unroll
  for (int ks = 0; ks < 3; ++ks) {
    bf16x8 a[4];
    #pragma unroll
    for (int mf = 0; mf < 4; ++mf)
      a[mf] = *(const bf16x8*)(&Al[(mf * 16 + l15) * 120 + ks * 32 + g * 8]);
    #pragma unroll
    for (int nf = 0; nf < 4; ++nf)
      #pragma unroll
      for (int mf = 0; mf < 4; ++mf)
        acc[mf][nf] = __builtin_amdgcn_mfma_f32_16x16x32_bf16(
            breg[ks * 4 + nf], a[mf], acc[mf][nf], 0, 0, 0);  // D[row=o][col=px]
  }

  // ---- epilogue: + b1 (no relu), packed 8B stores
  #pragma unroll
  for (int nf = 0; nf < 4; ++nf) {
    int o0 = wc0 + nf * 16 + 4 * g;
    f32x4 bv = *(const f32x4*)(b1 + o0);
    #pragma unroll
    for (int mf = 0; mf < 4; ++mf) {
      int pixel = y * 128 + x0 + mf * 16 + l15;
      u16 p0 = f2bf(acc[mf][nf][0] + bv[0]);
      u16 p1 = f2bf(acc[mf][nf][1] + bv[1]);
      u16 p2 = f2bf(acc[mf][nf][2] + bv[2]);
      u16 p3 = f2bf(acc[mf][nf][3] + bv[3]);
      unsigned long long w =
          (unsigned long long)(p0 | ((uint32_t)p1 << 16)) |
          ((unsigned long long)(p2 | ((uint32_t)p3 << 16)) << 32);
      *(unsigned long long*)(h1pre + (((size_t)((b << 14) + pixel)) << 8) + o0) = w;
    }
  }
}

// ---------------------------------------------------------------- fused per-query MLP v14
// 256 thr / 4 waves, 2 tiles x 64 rows (32 queries) per block, 3750 blocks.
// Operand-swapped MFMA; XOR-swizzled Xl; wr-table in regs; bulk breg[32]/layer over
// 2 tiles; batched 16-load gather; 2 barriers/layer (loop-end barrier was redundant).
__global__ __launch_bounds__(256, 2) void mlp_kernel(
    const float* __restrict__ coord, const float* __restrict__ cell,
    const u16* __restrict__ h1pre,
    const u16* __restrict__ w2t, const u16* __restrict__ w3t, const u16* __restrict__ w4t,
    const float* __restrict__ w1, const float* __restrict__ b2, const float* __restrict__ b3,
    const float* __restrict__ b4, const float* __restrict__ w5, const float* __restrict__ b5,
    float* __restrict__ out) {
  __shared__ short Xl[2][64 * 256];  // [tile][row*256 + swizzled slot*8], rows 512B
  __shared__ float relv[128][4];
  __shared__ float area_l[128];
  __shared__ int   idx_l[128];       // (b<<14) + pixel
  __shared__ float predp[4][128];

  int tid = threadIdx.x;
  int lane = tid & 63, wave = tid >> 6;
  int g = lane >> 4, l15 = lane & 15;
  int wc0 = wave * 64;
  int xr = l15 & 7;                  // row-XOR for frag rows (row = mf*16+l15)
  int bid = blockIdx.x;              // 3750 blocks x 32 queries

  // ---- wr rel-weight table -> registers (thread owns cols c16*8..c16*8+7)
  int c16 = tid & 31;
  float wrr[4][8];
  {
    const float* wr = w1 + 576 * 256;   // [4][256] fp32
    #pragma unroll
    for (int a = 0; a < 4; ++a) {
      f32x4 u0 = *(const f32x4*)(wr + a * 256 + c16 * 8);
      f32x4 u1 = *(const f32x4*)(wr + a * 256 + c16 * 8 + 4);
      #pragma unroll
      for (int e = 0; e < 4; ++e) { wrr[a][e] = u0[e]; wrr[a][4 + e] = u1[e]; }
    }
  }

  // ---- geometry for all 128 rows
  if (tid < 128) {
    int t = tid >> 2, br = tid & 3;            // branch order: vx outer, vy inner
    int gq = bid * 32 + t;
    int b = gq / 30000;
    float c0 = coord[gq * 2 + 0];
    float c1 = coord[gq * 2 + 1];
    float ce0 = cell[gq * 2 + 0];
    float ce1 = cell[gq * 2 + 1];
    float vx = (br & 2) ? 1.0f : -1.0f;
    float vy = (br & 1) ? 1.0f : -1.0f;
    float s0 = c0 + vx * (1.0f / 128.0f) + 1e-6f;
    float s1 = c1 + vy * (1.0f / 128.0f) + 1e-6f;
    s0 = fminf(fmaxf(s0, -1.0f + 1e-6f), 1.0f - 1e-6f);
    s1 = fminf(fmaxf(s1, -1.0f + 1e-6f), 1.0f - 1e-6f);
    float fi = rintf((s0 + 1.0f) * 64.0f - 0.5f);
    float fj = rintf((s1 + 1.0f) * 64.0f - 0.5f);
    fi = fminf(fmaxf(fi, 0.0f), 127.0f);
    fj = fminf(fmaxf(fj, 0.0f), 127.0f);
    float qy = -1.0f + (2.0f * fi + 1.0f) / 128.0f;
    float qx = -1.0f + (2.0f * fj + 1.0f) / 128.0f;
    float rel0 = (c0 - qy) * 128.0f;
    float rel1 = (c1 - qx) * 128.0f;
    idx_l[tid] = (b << 14) + (int)fi * 128 + (int)fj;
    relv[tid][0] = rel0;
    relv[tid][1] = rel1;
    relv[tid][2] = ce0 * 128.0f;
    relv[tid][3] = ce1 * 128.0f;
    area_l[tid] = fabsf(rel0 * rel1) + 1e-9f;
  }
  __syncthreads();

  // ---- gather: ONE batch of 16x16B loads (both tiles), then process both tiles
  {
    short8 v[16];
    #pragma unroll
    for (int it = 0; it < 8; ++it) {
      int rl = it * 8 + (tid >> 5);
      v[it]     = *(const short8*)(h1pre + ((size_t)idx_l[rl] << 8) + c16 * 8);
      v[8 + it] = *(const short8*)(h1pre + ((size_t)idx_l[64 + rl] << 8) + c16 * 8);
    }
    __builtin_amdgcn_sched_barrier(0);  // keep all 16 loads batched
    #pragma unroll
    for (int t = 0; t < 2; ++t) {
      #pragma unroll
      for (int it = 0; it < 8; ++it) {
        int rl = it * 8 + (tid >> 5);
        int row = t * 64 + rl;
        float r0 = relv[row][0], r1 = relv[row][1], r2 = relv[row][2], r3 = relv[row][3];
        short8 xo;
        #pragma unroll
        for (int e = 0; e < 8; ++e) {
          float val = bf2f((u16)v[t * 8 + it][e]) + r0 * wrr[0][e] + r1 * wrr[1][e] +
                      r2 * wrr[2][e] + r3 * wrr[3][e];
          xo[e] = (short)bfbits(fmaxf(val, 0.0f));
        }
        *(short8*)(&Xl[t][rl * 256 + ((c16 ^ (rl & 7)) * 8)]) = xo;
      }
    }
  }
  __syncthreads();

  const u16* Wgs[3] = {w2t, w3t, w4t};
  const float* Bgs[3] = {b2, b3, b4};

  #pragma unroll
  for (int layer = 0; layer < 3; ++layer) {
    const u16* Wg = Wgs[layer];
    const float* bias = Bgs[layer];

    // one batched weight preload per layer (serves both tiles)
    bf16x8 breg[32];
    #pragma unroll
    for (int ks = 0; ks < 8; ++ks)
      #pragma unroll
      for (int nf = 0; nf < 4; ++nf)
        breg[ks * 4 + nf] =
            *(const bf16x8*)(Wg + (wc0 + nf * 16 + l15) * 256 + ks * 32 + g * 8);
    __builtin_amdgcn_sched_barrier(0);

    #pragma unroll
    for (int t = 0; t < 2; ++t) {
      f32x4 acc[4][4];
      #pragma unroll
      for (int mf = 0; mf < 4; ++mf)
        #pragma unroll
        for (int nf = 0; nf < 4; ++nf) acc[mf][nf] = (f32x4){0.f, 0.f, 0.f, 0.f};

      #pragma unroll
      for (int ks = 0; ks < 8; ++ks) {
        bf16x8 a[4];
        #pragma unroll
        for (int mf = 0; mf < 4; ++mf)
          a[mf] = *(const bf16x8*)(&Xl[t][(mf * 16 + l15) * 256 + (((ks * 4 + g) ^ xr) * 8)]);
        #pragma unroll
        for (int nf = 0; nf < 4; ++nf)
          #pragma unroll
          for (int mf = 0; mf < 4; ++mf)
            acc[mf][nf] = __builtin_amdgcn_mfma_f32_16x16x32_bf16(
                breg[ks * 4 + nf], a[mf], acc[mf][nf], 0, 0, 0);  // D[row=o][col=q]
      }

      __syncthreads();   // all waves done READING Xl[t] before overwrite
      if (layer < 2) {
        #pragma unroll
        for (int nf = 0; nf < 4; ++nf) {
          int o0 = wc0 + nf * 16 + 4 * g;           // 4 consecutive hidden units
          f32x4 bv = *(const f32x4*)(bias + o0);
          #pragma unroll
          for (int mf = 0; mf < 4; ++mf) {
            u16 p0 = bfbits(fmaxf(acc[mf][nf][0] + bv[0], 0.0f));
            u16 p1 = bfbits(fmaxf(acc[mf][nf][1] + bv[1], 0.0f));
            u16 p2 = bfbits(fmaxf(acc[mf][nf][2] + bv[2], 0.0f));
            u16 p3 = bfbits(fmaxf(acc[mf][nf][3] + bv[3], 0.0f));
            unsigned long long w =
                (unsigned long long)(p0 | ((uint32_t)p1 << 16)) |
                ((unsigned long long)(p2 | ((uint32_t)p3 << 16)) << 32);
            int idx = (mf * 16 + l15) * 256 + (((o0 >> 3) ^ xr) * 8) + (o0 & 7);
            *(unsigned long long*)(&Xl[t][idx]) = w;
          }
        }
      } else {
        // head: relu(acc+b4) dot w5; reduce over o: in-lane (nf,i) + shfl over g
        float s[4] = {0.f, 0.f, 0.f, 0.f};
        #pragma unroll
        for (int nf = 0; nf < 4; ++nf) {
          int o0 = wc0 + nf * 16 + 4 * g;
          f32x4 bv = *(const f32x4*)(b4 + o0);
          f32x4 wv = *(const f32x4*)(w5 + o0);
          #pragma unroll
          for (int mf = 0; mf < 4; ++mf)
            #pragma unroll
            for (int i = 0; i < 4; ++i)
              s[mf] += fmaxf(acc[mf][nf][i] + bv[i], 0.0f) * wv[i];
        }
        #pragma unroll
        for (int mf = 0; mf < 4; ++mf) {
          s[mf] += __shfl_xor(s[mf], 16, 64);
          s[mf] += __shfl_xor(s[mf], 32, 64);
        }
        if (lane < 16) {
          #pragma unroll
          for (int mf = 0; mf < 4; ++mf)
            predp[wave][t * 64 + mf * 16 + lane] = s[mf];
        }
      }
    }
    // NOTE: no loop-end barrier. Window analysis: [barB(L)] {epi-t1(L) writes Xl1 |
    // breg(L+1) | t0-kloop(L+1) reads Xl0} [barA(L+1)] {epi-t0(L+1) writes Xl0 |
    // t1-kloop(L+1) reads Xl1} -- no same-buffer write/read shares a window.
  }
  __syncthreads();   // predp (head) writes of all waves visible before ensemble

  // ---- local ensemble (areas diagonally swapped)
  if (tid < 32) {
    int gq = bid * 32 + tid;
    float pr[4], ar[4];
    #pragma unroll
    for (int br = 0; br < 4; ++br) {
      int r = tid * 4 + br;
      pr[br] = predp[0][r] + predp[1][r] + predp[2][r] + predp[3][r] + b5[0];
      ar[br] = area_l[r];
    }
    float tot = ar[0] + ar[1] + ar[2] + ar[3];
    float ret = 0.0f;
    #pragma unroll
    for (int br = 0; br < 4; ++br) ret += pr[br] * (ar[3 - br] / tot);
    out[gq] = ret;
  }
}

// ---------------------------------------------------------------- launch
extern "C" void kernel_launch(void* const* d_in, const int* in_sizes, int n_in,
                              void* d_out, int out_size, void* d_ws, size_t ws_size,
                              hipStream_t stream) {
  const float* inp    = (const float*)d_in[0];
  const float* coord  = (const float*)d_in[1];
  const float* cell   = (const float*)d_in[2];
  const float* conv_w = (const float*)d_in[3];
  const float* conv_b = (const float*)d_in[4];
  const float* w1 = (const float*)d_in[5];
  const float* b1 = (const float*)d_in[6];
  const float* w2 = (const float*)d_in[7];
  const float* b2 = (const float*)d_in[8];
  const float* w3 = (const float*)d_in[9];
  const float* b3 = (const float*)d_in[10];
  const float* w4 = (const float*)d_in[11];
  const float* b4 = (const float*)d_in[12];
  const float* w5 = (const float*)d_in[13];
  const float* b5 = (const float*)d_in[14];
  float* out = (float*)d_out;

  char* ws = (char*)d_ws;
  u16* h1pre = (u16*)(ws);
  u16* W2t   = (u16*)(ws + 33554432);
  u16* w2t   = (u16*)(ws + 33603584);
  u16* w3t   = (u16*)(ws + 33734656);
  u16* w4t   = (u16*)(ws + 33865728);

  hipLaunchKernelGGL(prep_weights, dim3(864), dim3(256), 0, stream,
                     w1, w2, w3, w4, conv_w, conv_b, W2t, w2t, w3t, w4t);
  hipLaunchKernelGGL(h1pre_kernel, dim3(1024), dim3(256), 0, stream,
                     inp, W2t, b1, h1pre);
  hipLaunchKernelGGL(mlp_kernel, dim3(3750), dim3(256), 0, stream,
                     coord, cell, h1pre, w2t, w3t, w4t, w1, b2, b3, b4, w5, b5, out);
}

// Round 16
// 310.363 us; speedup vs baseline: 1.0600x; 1.0600x over previous
//
#include <hip/hip_runtime.h>
#include <stdint.h>

// LIIF fused inference for MI355X (gfx950).  FINAL (= v10, best verified: 311us).
// B=4, C=64, H=W=128, Q=30000, HID=256, IN_DIM=580.
//
// Structure:
//   prep_weights: composes conv1+layer1 weights algebraically (K=90->96 GEMM);
//                 transposes w2..w4 to [o][k] bf16.
//   h1pre_kernel: h1pre[p][o] via composed K=96 MFMA GEMM (conv1+feat eliminated).
//   mlp_kernel:   2 tiles x 64 rows (32 queries)/block; batched 16-load gather;
//                 reg wr-table; XOR-swizzled Xl; bulk breg[32]/layer over 2 tiles;
//                 operand-swapped 16x16x32 MFMA (D[o][q]); packed ds_write epilogue;
//                 3 barriers/layer (loop-end barrier REQUIRED: acts as reg-pressure
//                 fence -- removing it (v14) caused spills, +22us).
// Explored & closed: occupancy>2blk/CU spills (v7/v8/v12); weight streaming
// re-exposes latency (v3/v8); 32x32 MFMA neutral (v11); setprio neutral (v13).
//
// ws layout (33,996,800 bytes used):
//   h1_pre bf16  [0,        33554432)
//   W2t    bf16  [33554432, 33603584)   [256][96]
//   w2t    bf16  [33603584, 33734656)   [256][256]  (w2t[o][k] = w2[k][o])
//   w3t    bf16  [33734656, 33865728)
//   w4t    bf16  [33865728, 33996800)

typedef unsigned short u16;
typedef __attribute__((ext_vector_type(8))) short   short8;
typedef __attribute__((ext_vector_type(8))) __bf16  bf16x8;
typedef __attribute__((ext_vector_type(4))) float   f32x4;

__device__ __forceinline__ float bf2f(u16 u) {
  union { uint32_t i; float f; } v; v.i = ((uint32_t)u) << 16; return v.f;
}
__device__ __forceinline__ u16 f2bf(float f) {            // manual RNE (cold kernels)
  union { float f; uint32_t i; } v; v.f = f;
  return (u16)((v.i + 0x7FFFu + ((v.i >> 16) & 1u)) >> 16);
}
__device__ __forceinline__ u16 bfbits(float f) {          // native cast (hot kernel)
  union { __bf16 h; u16 u; } c; c.h = (__bf16)f; return c.u;
}

// ---------------------------------------------------------------- weights prep
__global__ void prep_weights(const float* __restrict__ w1, const float* __restrict__ w2,
                             const float* __restrict__ w3, const float* __restrict__ w4,
                             const float* __restrict__ cw, const float* __restrict__ cb,
                             u16* __restrict__ W2t, u16* __restrict__ w2t,
                             u16* __restrict__ w3t, u16* __restrict__ w4t) {
  int tid = blockIdx.x * 256 + threadIdx.x;
  if (tid < 24576) {
    int o = tid / 96, k = tid - o * 96;
    float s = 0.0f;
    if (k < 90) {
      int t = k / 10, j = k - t * 10;
      if (j == 9) {
        for (int c = 0; c < 64; ++c) s += cb[c] * w1[(c * 9 + t) * 256 + o];
      } else {
        for (int c = 0; c < 64; ++c) s += cw[c * 9 + j] * w1[(c * 9 + t) * 256 + o];
      }
    }
    W2t[o * 96 + k] = f2bf(s);
  } else {
    int u = tid - 24576;
    if (u < 3 * 65536) {
      int layer = u >> 16, r = u & 65535;
      int o = r >> 8, k = r & 255;
      const float* src = (layer == 0) ? w2 : (layer == 1) ? w3 : w4;
      u16* dst = (layer == 0) ? w2t : (layer == 1) ? w3t : w4t;
      dst[o * 256 + k] = f2bf(src[k * 256 + o]);
    }
  }
}

// ---------------------------------------------------------------- h1pre: composed K=96 GEMM
__global__ __launch_bounds__(256) void h1pre_kernel(const float* __restrict__ inp,
                                                    const u16* __restrict__ W2t,
                                                    const float* __restrict__ b1,
                                                    u16* __restrict__ h1pre) {
  __shared__ short Al[64 * 120];   // row = 120 shorts = 240 B

  int tid = threadIdx.x;
  int lane = tid & 63, wave = tid >> 6;
  int g = lane >> 4, l15 = lane & 15;
  int wc0 = wave * 64;
  int bid = blockIdx.x;
  int b = bid >> 8, rem = bid & 255;
  int y = rem >> 1, x0 = (rem & 1) << 6;

  // ---- build A: 4 threads per pixel, thread q covers k = q*24 .. q*24+23
  {
    int px = tid >> 2, q = tid & 3;
    int x = x0 + px;
    const float* ip = inp + b * 16384;
    #pragma unroll
    for (int c8 = 0; c8 < 3; ++c8) {
      short8 av;
      #pragma unroll
      for (int e = 0; e < 8; ++e) {
        int k = q * 24 + c8 * 8 + e;
        float val = 0.0f;
        if (k < 90) {
          int t = k / 10, j = k - t * 10;
          int dh = t / 3 - 1, dw = t % 3 - 1;
          int yy = y + dh, xx = x + dw;
          bool m = (yy >= 0) && (yy < 128) && (xx >= 0) && (xx < 128);
          if (j == 9) {
            val = m ? 1.0f : 0.0f;
          } else {
            int sh = j / 3 - 1, sw = j % 3 - 1;
            int r = yy + sh, c = xx + sw;
            val = (m && r >= 0 && r < 128 && c >= 0 && c < 128) ? ip[r * 128 + c] : 0.0f;
          }
        }
        av[e] = (short)f2bf(val);
      }
      *(short8*)(&Al[px * 120 + q * 24 + c8 * 8]) = av;
    }
  }
  __syncthreads();

  // ---- GEMM: K=96 in 3 k-steps, bulk breg[12], operand-swapped 16x16 MFMA
  bf16x8 breg[12];
  #pragma unroll
  for (int ks = 0; ks < 3; ++ks)
    #pragma unroll
    for (int nf = 0; nf < 4; ++nf)
      breg[ks * 4 + nf] =
          *(const bf16x8*)(W2t + (wc0 + nf * 16 + l15) * 96 + ks * 32 + g * 8);

  f32x4 acc[4][4];
  #pragma unroll
  for (int mf = 0; mf < 4; ++mf)
    #pragma unroll
    for (int nf = 0; nf < 4; ++nf) acc[mf][nf] = (f32x4){0.f, 0.f, 0.f, 0.f};

  #pragma unroll
  for (int ks = 0; ks < 3; ++ks) {
    bf16x8 a[4];
    #pragma unroll
    for (int mf = 0; mf < 4; ++mf)
      a[mf] = *(const bf16x8*)(&Al[(mf * 16 + l15) * 120 + ks * 32 + g * 8]);
    #pragma unroll
    for (int nf = 0; nf < 4; ++nf)
      #pragma unroll
      for (int mf = 0; mf < 4; ++mf)
        acc[mf][nf] = __builtin_amdgcn_mfma_f32_16x16x32_bf16(
            breg[ks * 4 + nf], a[mf], acc[mf][nf], 0, 0, 0);  // D[row=o][col=px]
  }

  // ---- epilogue: + b1 (no relu), packed 8B stores
  #pragma unroll
  for (int nf = 0; nf < 4; ++nf) {
    int o0 = wc0 + nf * 16 + 4 * g;
    f32x4 bv = *(const f32x4*)(b1 + o0);
    #pragma unroll
    for (int mf = 0; mf < 4; ++mf) {
      int pixel = y * 128 + x0 + mf * 16 + l15;
      u16 p0 = f2bf(acc[mf][nf][0] + bv[0]);
      u16 p1 = f2bf(acc[mf][nf][1] + bv[1]);
      u16 p2 = f2bf(acc[mf][nf][2] + bv[2]);
      u16 p3 = f2bf(acc[mf][nf][3] + bv[3]);
      unsigned long long w =
          (unsigned long long)(p0 | ((uint32_t)p1 << 16)) |
          ((unsigned long long)(p2 | ((uint32_t)p3 << 16)) << 32);
      *(unsigned long long*)(h1pre + (((size_t)((b << 14) + pixel)) << 8) + o0) = w;
    }
  }
}

// ---------------------------------------------------------------- fused per-query MLP (v10)
// 256 thr / 4 waves, 2 tiles x 64 rows (32 queries) per block, 3750 blocks.
__global__ __launch_bounds__(256, 2) void mlp_kernel(
    const float* __restrict__ coord, const float* __restrict__ cell,
    const u16* __restrict__ h1pre,
    const u16* __restrict__ w2t, const u16* __restrict__ w3t, const u16* __restrict__ w4t,
    const float* __restrict__ w1, const float* __restrict__ b2, const float* __restrict__ b3,
    const float* __restrict__ b4, const float* __restrict__ w5, const float* __restrict__ b5,
    float* __restrict__ out) {
  __shared__ short Xl[2][64 * 256];  // [tile][row*256 + swizzled slot*8], rows 512B
  __shared__ float relv[128][4];
  __shared__ float area_l[128];
  __shared__ int   idx_l[128];       // (b<<14) + pixel
  __shared__ float predp[4][128];

  int tid = threadIdx.x;
  int lane = tid & 63, wave = tid >> 6;
  int g = lane >> 4, l15 = lane & 15;
  int wc0 = wave * 64;
  int xr = l15 & 7;                  // row-XOR for frag rows (row = mf*16+l15)
  int bid = blockIdx.x;              // 3750 blocks x 32 queries

  // ---- wr rel-weight table -> registers (thread owns cols c16*8..c16*8+7)
  int c16 = tid & 31;
  float wrr[4][8];
  {
    const float* wr = w1 + 576 * 256;   // [4][256] fp32
    #pragma unroll
    for (int a = 0; a < 4; ++a) {
      f32x4 u0 = *(const f32x4*)(wr + a * 256 + c16 * 8);
      f32x4 u1 = *(const f32x4*)(wr + a * 256 + c16 * 8 + 4);
      #pragma unroll
      for (int e = 0; e < 4; ++e) { wrr[a][e] = u0[e]; wrr[a][4 + e] = u1[e]; }
    }
  }

  // ---- geometry for all 128 rows
  if (tid < 128) {
    int t = tid >> 2, br = tid & 3;            // branch order: vx outer, vy inner
    int gq = bid * 32 + t;
    int b = gq / 30000;
    float c0 = coord[gq * 2 + 0];
    float c1 = coord[gq * 2 + 1];
    float ce0 = cell[gq * 2 + 0];
    float ce1 = cell[gq * 2 + 1];
    float vx = (br & 2) ? 1.0f : -1.0f;
    float vy = (br & 1) ? 1.0f : -1.0f;
    float s0 = c0 + vx * (1.0f / 128.0f) + 1e-6f;
    float s1 = c1 + vy * (1.0f / 128.0f) + 1e-6f;
    s0 = fminf(fmaxf(s0, -1.0f + 1e-6f), 1.0f - 1e-6f);
    s1 = fminf(fmaxf(s1, -1.0f + 1e-6f), 1.0f - 1e-6f);
    float fi = rintf((s0 + 1.0f) * 64.0f - 0.5f);
    float fj = rintf((s1 + 1.0f) * 64.0f - 0.5f);
    fi = fminf(fmaxf(fi, 0.0f), 127.0f);
    fj = fminf(fmaxf(fj, 0.0f), 127.0f);
    float qy = -1.0f + (2.0f * fi + 1.0f) / 128.0f;
    float qx = -1.0f + (2.0f * fj + 1.0f) / 128.0f;
    float rel0 = (c0 - qy) * 128.0f;
    float rel1 = (c1 - qx) * 128.0f;
    idx_l[tid] = (b << 14) + (int)fi * 128 + (int)fj;
    relv[tid][0] = rel0;
    relv[tid][1] = rel1;
    relv[tid][2] = ce0 * 128.0f;
    relv[tid][3] = ce1 * 128.0f;
    area_l[tid] = fabsf(rel0 * rel1) + 1e-9f;
  }
  __syncthreads();

  // ---- gather: ONE batch of 16x16B loads (both tiles), then process both tiles
  {
    short8 v[16];
    #pragma unroll
    for (int it = 0; it < 8; ++it) {
      int rl = it * 8 + (tid >> 5);
      v[it]     = *(const short8*)(h1pre + ((size_t)idx_l[rl] << 8) + c16 * 8);
      v[8 + it] = *(const short8*)(h1pre + ((size_t)idx_l[64 + rl] << 8) + c16 * 8);
    }
    __builtin_amdgcn_sched_barrier(0);  // keep all 16 loads batched
    #pragma unroll
    for (int t = 0; t < 2; ++t) {
      #pragma unroll
      for (int it = 0; it < 8; ++it) {
        int rl = it * 8 + (tid >> 5);
        int row = t * 64 + rl;
        float r0 = relv[row][0], r1 = relv[row][1], r2 = relv[row][2], r3 = relv[row][3];
        short8 xo;
        #pragma unroll
        for (int e = 0; e < 8; ++e) {
          float val = bf2f((u16)v[t * 8 + it][e]) + r0 * wrr[0][e] + r1 * wrr[1][e] +
                      r2 * wrr[2][e] + r3 * wrr[3][e];
          xo[e] = (short)bfbits(fmaxf(val, 0.0f));
        }
        *(short8*)(&Xl[t][rl * 256 + ((c16 ^ (rl & 7)) * 8)]) = xo;
      }
    }
  }
  __syncthreads();

  const u16* Wgs[3] = {w2t, w3t, w4t};
  const float* Bgs[3] = {b2, b3, b4};

  #pragma unroll
  for (int layer = 0; layer < 3; ++layer) {
    const u16* Wg = Wgs[layer];
    const float* bias = Bgs[layer];

    // one batched weight preload per layer (serves both tiles)
    bf16x8 breg[32];
    #pragma unroll
    for (int ks = 0; ks < 8; ++ks)
      #pragma unroll
      for (int nf = 0; nf < 4; ++nf)
        breg[ks * 4 + nf] =
            *(const bf16x8*)(Wg + (wc0 + nf * 16 + l15) * 256 + ks * 32 + g * 8);
    __builtin_amdgcn_sched_barrier(0);

    #pragma unroll
    for (int t = 0; t < 2; ++t) {
      f32x4 acc[4][4];
      #pragma unroll
      for (int mf = 0; mf < 4; ++mf)
        #pragma unroll
        for (int nf = 0; nf < 4; ++nf) acc[mf][nf] = (f32x4){0.f, 0.f, 0.f, 0.f};

      #pragma unroll
      for (int ks = 0; ks < 8; ++ks) {
        bf16x8 a[4];
        #pragma unroll
        for (int mf = 0; mf < 4; ++mf)
          a[mf] = *(const bf16x8*)(&Xl[t][(mf * 16 + l15) * 256 + (((ks * 4 + g) ^ xr) * 8)]);
        #pragma unroll
        for (int nf = 0; nf < 4; ++nf)
          #pragma unroll
          for (int mf = 0; mf < 4; ++mf)
            acc[mf][nf] = __builtin_amdgcn_mfma_f32_16x16x32_bf16(
                breg[ks * 4 + nf], a[mf], acc[mf][nf], 0, 0, 0);  // D[row=o][col=q]
      }

      __syncthreads();   // all waves done READING Xl[t] before overwrite
      if (layer < 2) {
        #pragma unroll
        for (int nf = 0; nf < 4; ++nf) {
          int o0 = wc0 + nf * 16 + 4 * g;           // 4 consecutive hidden units
          f32x4 bv = *(const f32x4*)(bias + o0);
          #pragma unroll
          for (int mf = 0; mf < 4; ++mf) {
            u16 p0 = bfbits(fmaxf(acc[mf][nf][0] + bv[0], 0.0f));
            u16 p1 = bfbits(fmaxf(acc[mf][nf][1] + bv[1], 0.0f));
            u16 p2 = bfbits(fmaxf(acc[mf][nf][2] + bv[2], 0.0f));
            u16 p3 = bfbits(fmaxf(acc[mf][nf][3] + bv[3], 0.0f));
            unsigned long long w =
                (unsigned long long)(p0 | ((uint32_t)p1 << 16)) |
                ((unsigned long long)(p2 | ((uint32_t)p3 << 16)) << 32);
            int idx = (mf * 16 + l15) * 256 + (((o0 >> 3) ^ xr) * 8) + (o0 & 7);
            *(unsigned long long*)(&Xl[t][idx]) = w;
          }
        }
      } else {
        // head: relu(acc+b4) dot w5; reduce over o: in-lane (nf,i) + shfl over g
        float s[4] = {0.f, 0.f, 0.f, 0.f};
        #pragma unroll
        for (int nf = 0; nf < 4; ++nf) {
          int o0 = wc0 + nf * 16 + 4 * g;
          f32x4 bv = *(const f32x4*)(b4 + o0);
          f32x4 wv = *(const f32x4*)(w5 + o0);
          #pragma unroll
          for (int mf = 0; mf < 4; ++mf)
            #pragma unroll
            for (int i = 0; i < 4; ++i)
              s[mf] += fmaxf(acc[mf][nf][i] + bv[i], 0.0f) * wv[i];
        }
        #pragma unroll
        for (int mf = 0; mf < 4; ++mf) {
          s[mf] += __shfl_xor(s[mf], 16, 64);
          s[mf] += __shfl_xor(s[mf], 32, 64);
        }
        if (lane < 16) {
          #pragma unroll
          for (int mf = 0; mf < 4; ++mf)
            predp[wave][t * 64 + mf * 16 + lane] = s[mf];
        }
      }
    }
    __syncthreads();   // epi writes visible before next layer / ensemble
                       // (also acts as reg-pressure fence: removing it spills, v14)
  }

  // ---- local ensemble (areas diagonally swapped)
  if (tid < 32) {
    int gq = bid * 32 + tid;
    float pr[4], ar[4];
    #pragma unroll
    for (int br = 0; br < 4; ++br) {
      int r = tid * 4 + br;
      pr[br] = predp[0][r] + predp[1][r] + predp[2][r] + predp[3][r] + b5[0];
      ar[br] = area_l[r];
    }
    float tot = ar[0] + ar[1] + ar[2] + ar[3];
    float ret = 0.0f;
    #pragma unroll
    for (int br = 0; br < 4; ++br) ret += pr[br] * (ar[3 - br] / tot);
    out[gq] = ret;
  }
}

// ---------------------------------------------------------------- launch
extern "C" void kernel_launch(void* const* d_in, const int* in_sizes, int n_in,
                              void* d_out, int out_size, void* d_ws, size_t ws_size,
                              hipStream_t stream) {
  const float* inp    = (const float*)d_in[0];
  const float* coord  = (const float*)d_in[1];
  const float* cell   = (const float*)d_in[2];
  const float* conv_w = (const float*)d_in[3];
  const float* conv_b = (const float*)d_in[4];
  const float* w1 = (const float*)d_in[5];
  const float* b1 = (const float*)d_in[6];
  const float* w2 = (const float*)d_in[7];
  const float* b2 = (const float*)d_in[8];
  const float* w3 = (const float*)d_in[9];
  const float* b3 = (const float*)d_in[10];
  const float* w4 = (const float*)d_in[11];
  const float* b4 = (const float*)d_in[12];
  const float* w5 = (const float*)d_in[13];
  const float* b5 = (const float*)d_in[14];
  float* out = (float*)d_out;

  char* ws = (char*)d_ws;
  u16* h1pre = (u16*)(ws);
  u16* W2t   = (u16*)(ws + 33554432);
  u16* w2t   = (u16*)(ws + 33603584);
  u16* w3t   = (u16*)(ws + 33734656);
  u16* w4t   = (u16*)(ws + 33865728);

  hipLaunchKernelGGL(prep_weights, dim3(864), dim3(256), 0, stream,
                     w1, w2, w3, w4, conv_w, conv_b, W2t, w2t, w3t, w4t);
  hipLaunchKernelGGL(h1pre_kernel, dim3(1024), dim3(256), 0, stream,
                     inp, W2t, b1, h1pre);
  hipLaunchKernelGGL(mlp_kernel, dim3(3750), dim3(256), 0, stream,
                     coord, cell, h1pre, w2t, w3t, w4t, w1, b2, b3, b4, w5, b5, out);
}